// Round 5
// baseline (503.727 us; speedup 1.0000x reference)
//
#include <hip/hip_runtime.h>
#include <stdint.h>

// TankModel: B=8192 independent chains, sequential nonlinear 4-tank scan,
// T=4096. 128 blocks x 64 lanes, one chain per lane, one block per CU ->
// wall time = per-wave serial instruction stream. r3 measured ~61 compiled
// inst/step (VALUBusy 8.7% / 12.5% occupancy at 176 cyc/step) vs ~32 ideal.
// This version is instruction-count surgery on r3's (memory-clean) skeleton:
//   - 16 swizzled LDS byte-offsets precomputed ONCE into VGPRs; buffer
//     parity is a single scalar add per tile -> zero per-use address VALU.
//   - 64-step tile body FULLY unrolled: no float4 rotation movs, mask is
//     exactly v_cmp_lt_i32 (inline const 0..63) + v_cndmask = 2 inst/step.
//   - all 16 ds_read_b128 issued up front per tile (~200 cyc once), then
//     4000+ cyc of compute with no lgkm stalls.
//   - staging via global_load_lds width=16 one tile ahead (zero VGPR cost,
//     XOR-swizzled source cols so lane-contiguous dest = conflict-free
//     8-phase ds_read_b128 later); outputs staged in LDS out-tile and
//     coop-stored as full-sector dwordx4 (r3's exact-131MB write traffic).

#define GLOBAL_AS __attribute__((address_space(1)))
#define LDS_AS    __attribute__((address_space(3)))

__device__ __forceinline__ void async_ld16(const float* gp, void* lds_ptr) {
    // lane i writes lds_ptr + i*16 bytes; gp is per-lane.
    __builtin_amdgcn_global_load_lds((const GLOBAL_AS void*)gp,
                                     (LDS_AS void*)lds_ptr, 16, 0, 0);
}

// LDS layout (bytes): in0 @0, in1 @16384, out0 @32768, out1 @49152
__global__ __launch_bounds__(64, 1)
void tank_kernel(
    const float* __restrict__ P,
    const int*   __restrict__ lengths,
    const float* __restrict__ S0,
    const float* __restrict__ AreaP,
    const float* __restrict__ p_r1h1, const float* __restrict__ p_r1h2,
    const float* __restrict__ p_h1h1, const float* __restrict__ p_h1h2,
    const float* __restrict__ p_ri2,  const float* __restrict__ p_ro2,
    const float* __restrict__ p_h2,
    const float* __restrict__ p_ri3,  const float* __restrict__ p_ro3,
    const float* __restrict__ p_h3,
    const float* __restrict__ p_ri4,  const float* __restrict__ p_ro4,
    float* __restrict__ Out,
    int B, int T)
{
    __shared__ char lds[65536];

    const int tid  = threadIdx.x;
    const int row0 = blockIdx.x * 64;
    const int myrow = row0 + tid;
    const int rowc = (myrow < B) ? myrow : (B - 1);

    // Uniform params -> SGPRs; folded: max(r*(w-h+p),0) == max(fma(r,w+p,-r*h),0)
    const float r1h1 = p_r1h1[0], r1h2 = p_r1h2[0];
    const float k1 = -r1h1 * p_h1h1[0];
    const float k2 = -r1h2 * p_h1h2[0];
    const float ri2 = p_ri2[0];
    const float ro2 = p_ro2[0];
    const float k3 = -ro2 * p_h2[0];
    const float ri3 = p_ri3[0];
    const float ro3 = p_ro3[0];
    const float k4 = -ro3 * p_h3[0];
    const float ri4 = p_ri4[0];
    const float ro4 = p_ro4[0];
    const float scale = AreaP[0] * (1.0f / 3.6f);

    float w1 = S0[0], w2 = S0[1], w3 = S0[2], w4 = S0[3];

    int len = lengths[rowc];
    if (len > T) len = T;
    if (len < 0) len = 0;

    const int sr = tid >> 4;   // staging subgroup (row = 4k+sr per pass k)
    const int j  = tid & 15;   // staging phys slot within a row

    // Per-lane swizzled in-tile byte offsets for compute reads / out writes.
    // Row tid, logical col-group q lives at phys slot q^(tid&15):
    // conflict-free 8-phase ds_read_b128 across the wave.
    int ofs[16];
    #pragma unroll
    for (int q = 0; q < 16; ++q)
        ofs[q] = tid * 256 + ((q ^ (tid & 15)) * 16);

    // Per-pass global element offsets (row base + XOR-swizzled column).
    int gidx[16];
    #pragma unroll
    for (int k = 0; k < 16; ++k) {
        int r  = 4 * k + sr;
        int rg = row0 + r; if (rg >= B) rg = B - 1;
        gidx[k] = rg * T + ((j ^ (r & 15)) << 2);
    }

    const int so_base = sr * 256 + j * 16;  // coop-read base within out tile

    // ---- prologue: stage tile 0 into in0 ----
    #pragma unroll
    for (int k = 0; k < 16; ++k)
        async_ld16(P + gidx[k], (void*)(lds + k * 1024));

#define STEP(pp, cidx, oo) do {                             \
        float t1 = w1 + (pp);                               \
        float a1 = fmaxf(fmaf(r1h1, t1, k1), 0.0f);         \
        float a2 = fmaxf(fmaf(r1h2, t1, k2), 0.0f);         \
        float m1 = fmaxf(t1, 0.0f);                         \
        float of1 = a1 + a2;                                \
        float s1 = t1 - of1;                                \
        w1 = fmaf(-ri2, m1, s1);                            \
        float t2 = fmaf(ri2, m1, w2);                       \
        float of2 = fmaxf(fmaf(ro2, t2, k3), 0.0f);         \
        float m2 = fmaxf(t2, 0.0f);                         \
        float s2 = t2 - of2;                                \
        w2 = fmaf(-ri3, m2, s2);                            \
        float t3 = fmaf(ri3, m2, w3);                       \
        float of3 = fmaxf(fmaf(ro3, t3, k4), 0.0f);         \
        float m3 = fmaxf(t3, 0.0f);                         \
        float s3 = t3 - of3;                                \
        w3 = fmaf(-ri4, m3, s3);                            \
        float t4 = fmaf(ri4, m3, w4);                       \
        float m4 = fmaxf(t4, 0.0f);                         \
        float of4 = ro4 * m4;                               \
        w4 = t4 - of4;                                      \
        float tot = ((of1 + of2) + (of3 + of4)) * scale;    \
        (oo) = ((cidx) < lrel) ? tot : 0.0f;                \
    } while (0)

    const int ntiles = T >> 6;   // 64 for T=4096
    for (int m = 0; m < ntiles; ++m) {
        // One barrier per tile: drains staging loads issued a full tile ago,
        // prev coop global stores, and orders LDS buffer reuse.
        __syncthreads();

        const int inoff = (m & 1) << 14;

        // 1) coop-store out-tile m-1 (fire-and-forget until next barrier)
        if (m > 0) {
            const int pout = ((m - 1) & 1) << 14;
            const int pcol = (m - 1) << 6;
            #pragma unroll
            for (int k = 0; k < 16; ++k) {
                float4 v = *(const float4*)(lds + 32768 + pout + so_base + k * 1024);
                *(float4*)(Out + gidx[k] + pcol) = v;
            }
        }

        // 2) stage tile m+1 (in flight across this tile's whole compute)
        if (m + 1 < ntiles) {
            const int nin  = ((m + 1) & 1) << 14;
            const int ncol = (m + 1) << 6;
            #pragma unroll
            for (int k = 0; k < 16; ++k)
                async_ld16(P + gidx[k] + ncol, (void*)(lds + nin + k * 1024));
        }

        // 3) compute 64 steps; all 16 ds_read_b128 issued up front
        const int lrel = len - (m << 6);
        float4 pin[16];
        #pragma unroll
        for (int q = 0; q < 16; ++q)
            pin[q] = *(const float4*)(lds + inoff + ofs[q]);

        #pragma unroll
        for (int q = 0; q < 16; ++q) {
            float4 ov;
            STEP(pin[q].x, 4 * q + 0, ov.x);
            STEP(pin[q].y, 4 * q + 1, ov.y);
            STEP(pin[q].z, 4 * q + 2, ov.z);
            STEP(pin[q].w, 4 * q + 3, ov.w);
            *(float4*)(lds + 32768 + inoff + ofs[q]) = ov;
        }
    }
#undef STEP

    // ---- epilogue: store out-tile ntiles-1 ----
    __syncthreads();
    {
        const int pout = ((ntiles - 1) & 1) << 14;
        const int pcol = (ntiles - 1) << 6;
        #pragma unroll
        for (int k = 0; k < 16; ++k) {
            float4 v = *(const float4*)(lds + 32768 + pout + so_base + k * 1024);
            *(float4*)(Out + gidx[k] + pcol) = v;
        }
    }
}

extern "C" void kernel_launch(void* const* d_in, const int* in_sizes, int n_in,
                              void* d_out, int out_size, void* d_ws, size_t ws_size,
                              hipStream_t stream) {
    const float* P        = (const float*)d_in[0];
    const int*   lengths  = (const int*)d_in[1];
    const float* S0       = (const float*)d_in[2];
    const float* Area     = (const float*)d_in[3];
    // d_in[4] = baseflow (unused by forward)
    const float* r1h1 = (const float*)d_in[5];
    const float* r1h2 = (const float*)d_in[6];
    const float* h1h1 = (const float*)d_in[7];
    const float* h1h2 = (const float*)d_in[8];
    const float* ri2  = (const float*)d_in[9];
    const float* ro2  = (const float*)d_in[10];
    const float* h2   = (const float*)d_in[11];
    const float* ri3  = (const float*)d_in[12];
    const float* ro3  = (const float*)d_in[13];
    const float* h3   = (const float*)d_in[14];
    const float* ri4  = (const float*)d_in[15];
    const float* ro4  = (const float*)d_in[16];
    float* out = (float*)d_out;

    const int B = in_sizes[1];
    const int T = in_sizes[0] / B;

    dim3 block(64);
    dim3 grid((B + 63) / 64);
    hipLaunchKernelGGL(tank_kernel, grid, block, 0, stream,
                       P, lengths, S0, Area,
                       r1h1, r1h2, h1h1, h1h2,
                       ri2, ro2, h2, ri3, ro3, h3, ri4, ro4,
                       out, B, T);
}